// Round 3
// baseline (541.026 us; speedup 1.0000x reference)
//
#include <hip/hip_runtime.h>

typedef unsigned short u16;
typedef __attribute__((ext_vector_type(8))) short short8;
typedef __attribute__((ext_vector_type(4))) unsigned short u16x4;
typedef __attribute__((ext_vector_type(4))) float f32x4;

#define DEV __device__ __forceinline__

DEV float bf2f(u16 u) { return __uint_as_float(((unsigned int)u) << 16); }
DEV u16 f2bf(float f) {
  unsigned int u = __float_as_uint(f);
  u += 0x7FFF + ((u >> 16) & 1);
  return (u16)(u >> 16);
}

DEV float redmax16(float v) {
  v = fmaxf(v, __shfl_xor(v, 1));
  v = fmaxf(v, __shfl_xor(v, 2));
  v = fmaxf(v, __shfl_xor(v, 4));
  v = fmaxf(v, __shfl_xor(v, 8));
  return v;
}
DEV float redsum16(float v) {
  v += __shfl_xor(v, 1);
  v += __shfl_xor(v, 2);
  v += __shfl_xor(v, 4);
  v += __shfl_xor(v, 8);
  return v;
}

// ---------------- transpose + cast f32 -> bf16, 32x32 tiles ----------------
__global__ __launch_bounds__(256) void transpose_f32_bf16(const float* __restrict__ in,
                                                          u16* __restrict__ out,
                                                          int R, int C) {
  __shared__ u16 tile[32][33];
  int tx = threadIdx.x & 31, ty = threadIdx.x >> 5;  // 32 x 8
  int r0 = blockIdx.y * 32, c0 = blockIdx.x * 32;
#pragma unroll
  for (int i = 0; i < 32; i += 8)
    tile[ty + i][tx] = f2bf(in[(size_t)(r0 + ty + i) * C + c0 + tx]);
  __syncthreads();
#pragma unroll
  for (int i = 0; i < 32; i += 8)
    out[(size_t)(c0 + ty + i) * R + r0 + tx] = tile[tx][ty + i];
}

// ---------------- RMSNorm: 8192 rows x 1024, f32 in -> bf16 out ----------------
__global__ __launch_bounds__(256) void rmsnorm_kernel(const float* __restrict__ x,
                                                      const float* __restrict__ w,
                                                      u16* __restrict__ xn) {
  int row = blockIdx.x, t = threadIdx.x;
  const float4* xr = reinterpret_cast<const float4*>(x + (size_t)row * 1024);
  float4 v = xr[t];
  float ss = v.x * v.x + v.y * v.y + v.z * v.z + v.w * v.w;
#pragma unroll
  for (int d = 1; d < 64; d <<= 1) ss += __shfl_xor(ss, d);
  __shared__ float red[4];
  if ((t & 63) == 0) red[t >> 6] = ss;
  __syncthreads();
  float tot = red[0] + red[1] + red[2] + red[3];
  float inv = rsqrtf(tot * (1.0f / 1024.0f) + 1e-6f);
  float4 wv = reinterpret_cast<const float4*>(w)[t];
  u16x4 o;
  o[0] = f2bf(v.x * inv * wv.x);
  o[1] = f2bf(v.y * inv * wv.y);
  o[2] = f2bf(v.z * inv * wv.z);
  o[3] = f2bf(v.w * inv * wv.w);
  *reinterpret_cast<u16x4*>(xn + (size_t)row * 1024 + t * 4) = o;
}

// ---------------- RoPE in-place on q,k halves of qkv (bf16), f32 sin/cos ------
__global__ __launch_bounds__(256) void rope_kernel(u16* __restrict__ qkv,
                                                   const float* __restrict__ sp,
                                                   const float* __restrict__ cp) {
  size_t i = (size_t)blockIdx.x * 256 + threadIdx.x;  // pair index, 8192*1024 total
  int row = (int)(i >> 10);
  int e2 = (int)(i & 1023);
  int pos = row & 4095;
  int elem = e2 * 2;  // within [q(1024) | k(1024)]
  int d = elem & 63;
  size_t off = (size_t)row * 3072 + elem;
  float xe = bf2f(qkv[off]), xo = bf2f(qkv[off + 1]);
  float s0 = sp[pos * 64 + d], s1 = sp[pos * 64 + d + 1];
  float c0 = cp[pos * 64 + d], c1 = cp[pos * 64 + d + 1];
  qkv[off] = f2bf(xe * c0 - xo * s0);
  qkv[off + 1] = f2bf(xo * c1 + xe * s1);
}

// ---------------- GEMM: C[M][N] = A[M][K] @ BT[N][K]^T + bias ----------------
// mode 0: bf16 out; mode 1: bf16 out + exact GELU; mode 2: f32 out
__global__ __launch_bounds__(256) void gemm_bt(const u16* __restrict__ A,
                                               const u16* __restrict__ BT,
                                               const float* __restrict__ bias,
                                               void* __restrict__ Cout,
                                               int K, int ldc, int mode) {
  __shared__ u16 Al[128 * 32];
  __shared__ u16 Bl[128 * 32];
  int t = threadIdx.x;
  int w = t >> 6, l = t & 63, c = l & 15, g = l >> 4;
  int wr = w >> 1, wc = w & 1;
  size_t m0 = (size_t)blockIdx.y * 128, n0 = (size_t)blockIdx.x * 128;

  f32x4 zero4 = {0.f, 0.f, 0.f, 0.f};
  f32x4 acc[4][4];
#pragma unroll
  for (int a = 0; a < 4; ++a)
#pragma unroll
    for (int b2 = 0; b2 < 4; ++b2) acc[a][b2] = zero4;

  const u16* Abase = A + m0 * K;
  const u16* Bbase = BT + n0 * K;

  for (int kt = 0; kt < K; kt += 32) {
    if (kt) __syncthreads();
#pragma unroll
    for (int j = 0; j < 2; ++j) {
      int idx = j * 256 + t;
      int row = idx >> 2, seg = idx & 3;
      const u16* ga = Abase + (size_t)row * K + kt + seg * 8;
      const u16* gb = Bbase + (size_t)row * K + kt + seg * 8;
      __builtin_amdgcn_global_load_lds(
          (const __attribute__((address_space(1))) unsigned int*)ga,
          (__attribute__((address_space(3))) unsigned int*)((char*)Al + idx * 16),
          16, 0, 0);
      __builtin_amdgcn_global_load_lds(
          (const __attribute__((address_space(1))) unsigned int*)gb,
          (__attribute__((address_space(3))) unsigned int*)((char*)Bl + idx * 16),
          16, 0, 0);
    }
    __syncthreads();
    short8 bv[4];
#pragma unroll
    for (int nj = 0; nj < 4; ++nj)
      bv[nj] = *reinterpret_cast<const short8*>(Bl + ((wc * 64 + 16 * nj + c) * 32 + 8 * g));
#pragma unroll
    for (int mi = 0; mi < 4; ++mi) {
      short8 av = *reinterpret_cast<const short8*>(Al + ((wr * 64 + 16 * mi + c) * 32 + 8 * g));
#pragma unroll
      for (int nj = 0; nj < 4; ++nj)
        acc[mi][nj] = __builtin_amdgcn_mfma_f32_16x16x32_bf16(av, bv[nj], acc[mi][nj], 0, 0, 0);
    }
  }

#pragma unroll
  for (int nj = 0; nj < 4; ++nj) {
    int col = (int)n0 + wc * 64 + 16 * nj + c;
    float bvv = bias[col];
#pragma unroll
    for (int mi = 0; mi < 4; ++mi) {
      size_t rbase = m0 + wr * 64 + 16 * mi + 4 * g;
#pragma unroll
      for (int r = 0; r < 4; ++r) {
        float f = acc[mi][nj][r] + bvv;
        if (mode == 1) f = 0.5f * f * (1.0f + erff(f * 0.70710678f));
        size_t oidx = (rbase + r) * (size_t)ldc + col;
        if (mode == 2)
          ((float*)Cout)[oidx] = f;
        else
          ((u16*)Cout)[oidx] = f2bf(f);
      }
    }
  }
}

// ---------------- sliding-window causal attention ----------------
// 4 waves per block; block covers 4 consecutive 64-query tiles of one (b,h).
// K/V tiles staged once in swizzled LDS via global_load_lds, shared by waves.
// grid = B*NH*(S/256) = 512, block = 256.
__global__ __launch_bounds__(256) void attn_kernel(const u16* __restrict__ qkv,
                                                   u16* __restrict__ comb) {
  __shared__ u16 Kl[4096];       // 64x64 bf16, XOR-swizzled rows
  __shared__ u16 Vl[4096];       // 64x64 bf16, XOR-swizzled rows
  __shared__ u16 Pl[4 * 64 * 72];  // per-wave P scratch (pi-permuted k layout)

  int wg = blockIdx.x;
  int qblk = wg & 15, h = (wg >> 4) & 15, b = wg >> 8;
  int w = threadIdx.x >> 6, l = threadIdx.x & 63, c = l & 15, g = l >> 4;
  int q0 = qblk * 256 + 64 * w;  // this wave's query tile start
  const u16* qb = qkv + (size_t)b * 4096 * 3072 + h * 64;
  const u16* kb = qb + 1024;
  const u16* vb = qb + 2048;
  u16* Pw = Pl + w * 64 * 72;

  // Q fragments (per wave, from global, once)
  short8 qf[4][2];
#pragma unroll
  for (int mi = 0; mi < 4; ++mi)
#pragma unroll
    for (int kk = 0; kk < 2; ++kk)
      qf[mi][kk] = *reinterpret_cast<const short8*>(
          qb + (size_t)(q0 + 16 * mi + c) * 3072 + 32 * kk + 8 * g);

  f32x4 zero4 = {0.f, 0.f, 0.f, 0.f};
  f32x4 o[4][4];
  float mr[4][4], lr[4][4];
#pragma unroll
  for (int a = 0; a < 4; ++a)
#pragma unroll
    for (int d2 = 0; d2 < 4; ++d2) {
      o[a][d2] = zero4;
      mr[a][d2] = -1e30f;
      lr[a][d2] = 0.f;
    }

  // swizzled staging source offsets for this lane (chunk-relative):
  // dest byte (within tile) = ch*1024 + 16*l -> row = 8*ch + (l>>3), slot = l&7
  // source slot = slot ^ (row&7) = (l&7) ^ ((l>>3)&7)
  int st_row = l >> 3;
  int st_slot = (l & 7) ^ ((l >> 3) & 7);

  for (int j = 0; j < 12; ++j) {
    int T = qblk * 4 - 8 + j;  // global k-tile index
    if (T >= 0) {
      // stage K (chunks 0-7) and V (chunks 8-15); wave w does chunks 4w..4w+3
#pragma unroll
      for (int cc = 0; cc < 4; ++cc) {
        int ch = 4 * w + cc;
        int isV = ch >> 3;
        int c2 = ch & 7;
        int row = 8 * c2 + st_row;
        const u16* src = (isV ? vb : kb) + (size_t)(T * 64 + row) * 3072 + st_slot * 8;
        u16* dstbase = isV ? Vl : Kl;
        __builtin_amdgcn_global_load_lds(
            (const __attribute__((address_space(1))) unsigned int*)src,
            (__attribute__((address_space(3))) unsigned int*)((char*)dstbase + c2 * 1024 + 16 * l),
            16, 0, 0);
      }
    }
    __syncthreads();

    bool active = (T >= 0) && (j >= w) && (j <= w + 8);
    if (active) {
      int kt0 = T * 64;
      f32x4 s[4][4];
#pragma unroll
      for (int a = 0; a < 4; ++a)
#pragma unroll
        for (int d2 = 0; d2 < 4; ++d2) s[a][d2] = zero4;

#pragma unroll
      for (int kk = 0; kk < 2; ++kk) {
        short8 kf[4];
#pragma unroll
        for (int nj = 0; nj < 4; ++nj) {
          int row = 16 * nj + c;
          int slot = (4 * kk + g) ^ (c & 7);
          kf[nj] = *reinterpret_cast<const short8*>(Kl + row * 64 + slot * 8);
        }
#pragma unroll
        for (int mi = 0; mi < 4; ++mi)
#pragma unroll
          for (int nj = 0; nj < 4; ++nj)
            s[mi][nj] = __builtin_amdgcn_mfma_f32_16x16x32_bf16(qf[mi][kk], kf[nj], s[mi][nj], 0, 0, 0);
      }

      bool mc = (j == w + 8), mw = (j == w);
#pragma unroll
      for (int mi = 0; mi < 4; ++mi)
#pragma unroll
        for (int nj = 0; nj < 4; ++nj)
#pragma unroll
          for (int r = 0; r < 4; ++r) {
            int qg = q0 + 16 * mi + 4 * g + r;
            int kg = kt0 + 16 * nj + c;
            float v = s[mi][nj][r] * 0.125f;
            if ((mc && kg > qg) || (mw && qg - kg >= 512)) v = -1e30f;
            s[mi][nj][r] = v;
          }

      float alpha[4][4];
#pragma unroll
      for (int mi = 0; mi < 4; ++mi)
#pragma unroll
        for (int r = 0; r < 4; ++r) {
          float tm = fmaxf(fmaxf(s[mi][0][r], s[mi][1][r]), fmaxf(s[mi][2][r], s[mi][3][r]));
          tm = redmax16(tm);
          float mn = fmaxf(mr[mi][r], tm);
          alpha[mi][r] = __expf(mr[mi][r] - mn);
          mr[mi][r] = mn;
          float rs = 0.f;
          u16x4 pk;
#pragma unroll
          for (int nj = 0; nj < 4; ++nj) {
            float p = __expf(s[mi][nj][r] - mn);
            rs += p;
            pk[nj] = f2bf(p);
          }
          rs = redsum16(rs);
          lr[mi][r] = lr[mi][r] * alpha[mi][r] + rs;
          // P stored with k-permutation pi(k)=4*(k&15)+(k>>4): packed b64 write
          *reinterpret_cast<u16x4*>(&Pw[(16 * mi + 4 * g + r) * 72 + 4 * c]) = pk;
        }
#pragma unroll
      for (int mi = 0; mi < 4; ++mi)
#pragma unroll
        for (int dj = 0; dj < 4; ++dj)
#pragma unroll
          for (int r = 0; r < 4; ++r) o[mi][dj][r] *= alpha[mi][r];

      // PV: A-frag from Pw (pi-space), B-frag = V scalars from swizzled LDS in pi-space
#pragma unroll
      for (int kk = 0; kk < 2; ++kk) {
        short8 pa[4];
#pragma unroll
        for (int mi = 0; mi < 4; ++mi)
          pa[mi] = *reinterpret_cast<const short8*>(&Pw[(16 * mi + c) * 72 + 32 * kk + 8 * g]);
        short8 bv[4];
#pragma unroll
        for (int dj = 0; dj < 4; ++dj)
#pragma unroll
          for (int i = 0; i < 8; ++i) {
            int jp = 32 * kk + 8 * g + i;
            int key = 16 * (jp & 3) + (jp >> 2);  // inverse of pi
            int ib = (16 * dj + c) * 2;
            int sb = ib ^ ((key & 7) << 4);
            bv[dj][i] = (short)Vl[key * 64 + (sb >> 1)];
          }
#pragma unroll
        for (int mi = 0; mi < 4; ++mi)
#pragma unroll
          for (int dj = 0; dj < 4; ++dj)
            o[mi][dj] = __builtin_amdgcn_mfma_f32_16x16x32_bf16(pa[mi], bv[dj], o[mi][dj], 0, 0, 0);
      }
    }
    __syncthreads();
  }

  u16* ob = comb + (size_t)(b * 4096 + q0) * 5120 + h * 64;
#pragma unroll
  for (int mi = 0; mi < 4; ++mi)
#pragma unroll
    for (int dj = 0; dj < 4; ++dj)
#pragma unroll
      for (int r = 0; r < 4; ++r)
        ob[(size_t)(16 * mi + 4 * g + r) * 5120 + 16 * dj + c] = f2bf(o[mi][dj][r] / lr[mi][r]);
}

// ---------------- launch ----------------
extern "C" void kernel_launch(void* const* d_in, const int* in_sizes, int n_in,
                              void* d_out, int out_size, void* d_ws, size_t ws_size,
                              hipStream_t stream) {
  const float* x = (const float*)d_in[0];
  const float* sinp = (const float*)d_in[1];
  const float* cosp = (const float*)d_in[2];
  const float* norm_w = (const float*)d_in[3];
  const float* w_qkv = (const float*)d_in[4];
  const float* b_qkv = (const float*)d_in[5];
  const float* w_in = (const float*)d_in[6];
  const float* b_in = (const float*)d_in[7];
  const float* w_out = (const float*)d_in[8];
  const float* b_out = (const float*)d_in[9];
  float* out = (float*)d_out;

  char* ws = (char*)d_ws;
  u16* xn = (u16*)(ws);                        // 8192*1024*2      = 16,777,216
  u16* qkv = (u16*)(ws + 16777216);            // 8192*3072*2      = 50,331,648
  u16* comb = (u16*)(ws + 67108864);           // 8192*5120*2      = 83,886,080
  u16* wqkvT = (u16*)(ws + 150994944);         // 3072*1024*2      = 6,291,456
  u16* winT = (u16*)(ws + 157286400);          // 4096*1024*2      = 8,388,608
  u16* woutT = (u16*)(ws + 165675008);         // 1024*5120*2      = 10,485,760

  transpose_f32_bf16<<<dim3(3072 / 32, 1024 / 32), 256, 0, stream>>>(w_qkv, wqkvT, 1024, 3072);
  transpose_f32_bf16<<<dim3(4096 / 32, 1024 / 32), 256, 0, stream>>>(w_in, winT, 1024, 4096);
  transpose_f32_bf16<<<dim3(1024 / 32, 5120 / 32), 256, 0, stream>>>(w_out, woutT, 5120, 1024);

  rmsnorm_kernel<<<8192, 256, 0, stream>>>(x, norm_w, xn);

  // qkv = xn @ w_qkv + b_qkv   (bf16 out)
  gemm_bt<<<dim3(3072 / 128, 8192 / 128), 256, 0, stream>>>(xn, wqkvT, b_qkv, qkv, 1024, 3072, 0);

  rope_kernel<<<32768, 256, 0, stream>>>(qkv, sinp, cosp);

  attn_kernel<<<512, 256, 0, stream>>>(qkv, comb);

  // ff = gelu(xn @ w_in + b_in) -> comb cols [1024, 5120)  (bf16 out)
  gemm_bt<<<dim3(4096 / 128, 8192 / 128), 256, 0, stream>>>(xn, winT, b_in, comb + 1024, 1024, 5120, 1);

  // out = comb @ w_out + b_out  (f32 out)
  gemm_bt<<<dim3(1024 / 128, 8192 / 128), 256, 0, stream>>>(comb, woutT, b_out, out, 5120, 1024, 2);
}

// Round 4
// 514.344 us; speedup vs baseline: 1.0519x; 1.0519x over previous
//
#include <hip/hip_runtime.h>

typedef unsigned short u16;
typedef __attribute__((ext_vector_type(8))) short short8;
typedef __attribute__((ext_vector_type(4))) unsigned short u16x4;
typedef __attribute__((ext_vector_type(4))) float f32x4;

#define DEV __device__ __forceinline__

DEV float bf2f(u16 u) { return __uint_as_float(((unsigned int)u) << 16); }
DEV u16 f2bf(float f) {
  unsigned int u = __float_as_uint(f);
  u += 0x7FFF + ((u >> 16) & 1);
  return (u16)(u >> 16);
}

DEV float redmax16(float v) {
  v = fmaxf(v, __shfl_xor(v, 1));
  v = fmaxf(v, __shfl_xor(v, 2));
  v = fmaxf(v, __shfl_xor(v, 4));
  v = fmaxf(v, __shfl_xor(v, 8));
  return v;
}
DEV float redsum16(float v) {
  v += __shfl_xor(v, 1);
  v += __shfl_xor(v, 2);
  v += __shfl_xor(v, 4);
  v += __shfl_xor(v, 8);
  return v;
}

// ---------------- transpose + cast f32 -> bf16, 32x32 tiles ----------------
__global__ __launch_bounds__(256) void transpose_f32_bf16(const float* __restrict__ in,
                                                          u16* __restrict__ out,
                                                          int R, int C) {
  __shared__ u16 tile[32][33];
  int tx = threadIdx.x & 31, ty = threadIdx.x >> 5;  // 32 x 8
  int r0 = blockIdx.y * 32, c0 = blockIdx.x * 32;
#pragma unroll
  for (int i = 0; i < 32; i += 8)
    tile[ty + i][tx] = f2bf(in[(size_t)(r0 + ty + i) * C + c0 + tx]);
  __syncthreads();
#pragma unroll
  for (int i = 0; i < 32; i += 8)
    out[(size_t)(c0 + ty + i) * R + r0 + tx] = tile[tx][ty + i];
}

// ---------------- transpose V third of qkv -> vT[b,h][64][4096] -------------
__global__ __launch_bounds__(256) void transpose_v(const u16* __restrict__ qkv,
                                                   u16* __restrict__ vT) {
  __shared__ u16 tile[32][33];
  int tx = threadIdx.x & 31, ty = threadIdx.x >> 5;  // 32 x 8
  int s0 = blockIdx.x * 32, d0 = blockIdx.y * 32;
  int bh = blockIdx.z;
  const u16* src = qkv + (size_t)(bh >> 4) * 4096 * 3072 + 2048 + (bh & 15) * 64;
#pragma unroll
  for (int i = 0; i < 32; i += 8)
    tile[ty + i][tx] = src[(size_t)(s0 + ty + i) * 3072 + d0 + tx];
  __syncthreads();
  u16* dst = vT + (size_t)bh * 64 * 4096;
#pragma unroll
  for (int i = 0; i < 32; i += 8)
    dst[(size_t)(d0 + ty + i) * 4096 + s0 + tx] = tile[tx][ty + i];
}

// ---------------- RMSNorm: 8192 rows x 1024, f32 in -> bf16 out ----------------
__global__ __launch_bounds__(256) void rmsnorm_kernel(const float* __restrict__ x,
                                                      const float* __restrict__ w,
                                                      u16* __restrict__ xn) {
  int row = blockIdx.x, t = threadIdx.x;
  const float4* xr = reinterpret_cast<const float4*>(x + (size_t)row * 1024);
  float4 v = xr[t];
  float ss = v.x * v.x + v.y * v.y + v.z * v.z + v.w * v.w;
#pragma unroll
  for (int d = 1; d < 64; d <<= 1) ss += __shfl_xor(ss, d);
  __shared__ float red[4];
  if ((t & 63) == 0) red[t >> 6] = ss;
  __syncthreads();
  float tot = red[0] + red[1] + red[2] + red[3];
  float inv = rsqrtf(tot * (1.0f / 1024.0f) + 1e-6f);
  float4 wv = reinterpret_cast<const float4*>(w)[t];
  u16x4 o;
  o[0] = f2bf(v.x * inv * wv.x);
  o[1] = f2bf(v.y * inv * wv.y);
  o[2] = f2bf(v.z * inv * wv.z);
  o[3] = f2bf(v.w * inv * wv.w);
  *reinterpret_cast<u16x4*>(xn + (size_t)row * 1024 + t * 4) = o;
}

// ------- RoPE in-place on q,k halves of qkv (bf16); q additionally *0.125 ----
__global__ __launch_bounds__(256) void rope_kernel(u16* __restrict__ qkv,
                                                   const float* __restrict__ sp,
                                                   const float* __restrict__ cp) {
  size_t i = (size_t)blockIdx.x * 256 + threadIdx.x;  // pair index, 8192*1024 total
  int row = (int)(i >> 10);
  int e2 = (int)(i & 1023);
  int pos = row & 4095;
  int elem = e2 * 2;  // within [q(1024) | k(1024)]
  int d = elem & 63;
  size_t off = (size_t)row * 3072 + elem;
  float sc = (elem < 1024) ? 0.125f : 1.0f;  // fold 1/sqrt(64) into q (exact)
  float xe = bf2f(qkv[off]), xo = bf2f(qkv[off + 1]);
  float s0 = sp[pos * 64 + d], s1 = sp[pos * 64 + d + 1];
  float c0 = cp[pos * 64 + d], c1 = cp[pos * 64 + d + 1];
  qkv[off] = f2bf((xe * c0 - xo * s0) * sc);
  qkv[off + 1] = f2bf((xo * c1 + xe * s1) * sc);
}

// ---------------- GEMM: C[M][N] = A[M][K] @ BT[N][K]^T + bias ----------------
// mode 0: bf16 out; mode 1: bf16 out + exact GELU; mode 2: f32 out
__global__ __launch_bounds__(256) void gemm_bt(const u16* __restrict__ A,
                                               const u16* __restrict__ BT,
                                               const float* __restrict__ bias,
                                               void* __restrict__ Cout,
                                               int K, int ldc, int mode) {
  __shared__ u16 Al[128 * 32];
  __shared__ u16 Bl[128 * 32];
  int t = threadIdx.x;
  int w = t >> 6, l = t & 63, c = l & 15, g = l >> 4;
  int wr = w >> 1, wc = w & 1;
  size_t m0 = (size_t)blockIdx.y * 128, n0 = (size_t)blockIdx.x * 128;

  f32x4 zero4 = {0.f, 0.f, 0.f, 0.f};
  f32x4 acc[4][4];
#pragma unroll
  for (int a = 0; a < 4; ++a)
#pragma unroll
    for (int b2 = 0; b2 < 4; ++b2) acc[a][b2] = zero4;

  const u16* Abase = A + m0 * K;
  const u16* Bbase = BT + n0 * K;

  for (int kt = 0; kt < K; kt += 32) {
    if (kt) __syncthreads();
#pragma unroll
    for (int j = 0; j < 2; ++j) {
      int idx = j * 256 + t;
      int row = idx >> 2, seg = idx & 3;
      const u16* ga = Abase + (size_t)row * K + kt + seg * 8;
      const u16* gb = Bbase + (size_t)row * K + kt + seg * 8;
      __builtin_amdgcn_global_load_lds(
          (const __attribute__((address_space(1))) unsigned int*)ga,
          (__attribute__((address_space(3))) unsigned int*)((char*)Al + idx * 16),
          16, 0, 0);
      __builtin_amdgcn_global_load_lds(
          (const __attribute__((address_space(1))) unsigned int*)gb,
          (__attribute__((address_space(3))) unsigned int*)((char*)Bl + idx * 16),
          16, 0, 0);
    }
    __syncthreads();
    short8 bv[4];
#pragma unroll
    for (int nj = 0; nj < 4; ++nj)
      bv[nj] = *reinterpret_cast<const short8*>(Bl + ((wc * 64 + 16 * nj + c) * 32 + 8 * g));
#pragma unroll
    for (int mi = 0; mi < 4; ++mi) {
      short8 av = *reinterpret_cast<const short8*>(Al + ((wr * 64 + 16 * mi + c) * 32 + 8 * g));
#pragma unroll
      for (int nj = 0; nj < 4; ++nj)
        acc[mi][nj] = __builtin_amdgcn_mfma_f32_16x16x32_bf16(av, bv[nj], acc[mi][nj], 0, 0, 0);
    }
  }

#pragma unroll
  for (int nj = 0; nj < 4; ++nj) {
    int col = (int)n0 + wc * 64 + 16 * nj + c;
    float bvv = bias[col];
#pragma unroll
    for (int mi = 0; mi < 4; ++mi) {
      size_t rbase = m0 + wr * 64 + 16 * mi + 4 * g;
#pragma unroll
      for (int r = 0; r < 4; ++r) {
        float f = acc[mi][nj][r] + bvv;
        if (mode == 1) f = 0.5f * f * (1.0f + erff(f * 0.70710678f));
        size_t oidx = (rbase + r) * (size_t)ldc + col;
        if (mode == 2)
          ((float*)Cout)[oidx] = f;
        else
          ((u16*)Cout)[oidx] = f2bf(f);
      }
    }
  }
}

// ---------------- sliding-window causal attention ----------------
// 1 wave per 64-query tile, no barriers. grid = 2048, block = 64.
// Q pre-scaled by 0.125. K frags direct global; V frags direct from vT.
// P through per-wave LDS in natural k-order.
__global__ __launch_bounds__(64) void attn_kernel(const u16* __restrict__ qkv,
                                                  const u16* __restrict__ vT,
                                                  u16* __restrict__ comb) {
  int wg = blockIdx.x;
  int qt = wg & 63, h = (wg >> 6) & 15, b = wg >> 10;
  int l = threadIdx.x, c = l & 15, g = l >> 4;
  int q0 = qt * 64;
  const u16* qb = qkv + (size_t)b * 4096 * 3072 + h * 64;
  const u16* kb = qb + 1024;
  const u16* vt = vT + (size_t)(b * 16 + h) * 64 * 4096;
  __shared__ u16 Pl[64 * 72];

  short8 qf[4][2];
#pragma unroll
  for (int mi = 0; mi < 4; ++mi)
#pragma unroll
    for (int kk = 0; kk < 2; ++kk)
      qf[mi][kk] = *reinterpret_cast<const short8*>(
          qb + (size_t)(q0 + 16 * mi + c) * 3072 + 32 * kk + 8 * g);

  f32x4 zero4 = {0.f, 0.f, 0.f, 0.f};
  f32x4 o[4][4];
  float mr[4][4], lr[4][4];
#pragma unroll
  for (int a = 0; a < 4; ++a)
#pragma unroll
    for (int d2 = 0; d2 < 4; ++d2) {
      o[a][d2] = zero4;
      mr[a][d2] = -1e30f;
      lr[a][d2] = 0.f;
    }

  int t_lo = qt >= 8 ? qt - 8 : 0;
  for (int tt = t_lo; tt <= qt; ++tt) {
    int kt0 = tt * 64;
    f32x4 s[4][4];
#pragma unroll
    for (int a = 0; a < 4; ++a)
#pragma unroll
      for (int d2 = 0; d2 < 4; ++d2) s[a][d2] = zero4;

#pragma unroll
    for (int kk = 0; kk < 2; ++kk) {
      short8 kf[4];
#pragma unroll
      for (int nj = 0; nj < 4; ++nj)
        kf[nj] = *reinterpret_cast<const short8*>(
            kb + (size_t)(kt0 + 16 * nj + c) * 3072 + 32 * kk + 8 * g);
#pragma unroll
      for (int mi = 0; mi < 4; ++mi)
#pragma unroll
        for (int nj = 0; nj < 4; ++nj)
          s[mi][nj] = __builtin_amdgcn_mfma_f32_16x16x32_bf16(qf[mi][kk], kf[nj], s[mi][nj], 0, 0, 0);
    }

    // mask only on the 2 boundary tiles (wave-uniform branch)
    bool mc = (tt == qt), mw = (tt == qt - 8);
    if (mc | mw) {
#pragma unroll
      for (int mi = 0; mi < 4; ++mi)
#pragma unroll
        for (int nj = 0; nj < 4; ++nj)
#pragma unroll
          for (int r = 0; r < 4; ++r) {
            int qg = q0 + 16 * mi + 4 * g + r;
            int kg = kt0 + 16 * nj + c;
            if ((mc && kg > qg) || (mw && qg - kg >= 512)) s[mi][nj][r] = -1e30f;
          }
    }

#pragma unroll
    for (int mi = 0; mi < 4; ++mi)
#pragma unroll
      for (int r = 0; r < 4; ++r) {
        float tm = fmaxf(fmaxf(s[mi][0][r], s[mi][1][r]), fmaxf(s[mi][2][r], s[mi][3][r]));
        tm = redmax16(tm);
        float mn = fmaxf(mr[mi][r], tm);
        float a = __expf(mr[mi][r] - mn);
        mr[mi][r] = mn;
        float rs = 0.f;
        u16* pp = &Pl[(16 * mi + 4 * g + r) * 72 + c];
#pragma unroll
        for (int nj = 0; nj < 4; ++nj) {
          float p = __expf(s[mi][nj][r] - mn);
          rs += p;
          pp[16 * nj] = f2bf(p);  // natural k order, imm-offset ds_write_b16
        }
        rs = redsum16(rs);
        lr[mi][r] = lr[mi][r] * a + rs;
#pragma unroll
        for (int dj = 0; dj < 4; ++dj) o[mi][dj][r] *= a;
      }

    // PV: A-frag from Pl (natural order), B-frag = k-contiguous rows of vT
#pragma unroll
    for (int kk = 0; kk < 2; ++kk) {
      short8 pa[4];
#pragma unroll
      for (int mi = 0; mi < 4; ++mi)
        pa[mi] = *reinterpret_cast<const short8*>(&Pl[(16 * mi + c) * 72 + 32 * kk + 8 * g]);
      short8 bv[4];
#pragma unroll
      for (int dj = 0; dj < 4; ++dj)
        bv[dj] = *reinterpret_cast<const short8*>(
            vt + (size_t)(16 * dj + c) * 4096 + kt0 + 32 * kk + 8 * g);
#pragma unroll
      for (int mi = 0; mi < 4; ++mi)
#pragma unroll
        for (int dj = 0; dj < 4; ++dj)
          o[mi][dj] = __builtin_amdgcn_mfma_f32_16x16x32_bf16(pa[mi], bv[dj], o[mi][dj], 0, 0, 0);
    }
  }

  u16* ob = comb + (size_t)(b * 4096 + q0) * 5120 + h * 64;
#pragma unroll
  for (int mi = 0; mi < 4; ++mi)
#pragma unroll
    for (int r = 0; r < 4; ++r) {
      float inv = __builtin_amdgcn_rcpf(lr[mi][r]);
#pragma unroll
      for (int dj = 0; dj < 4; ++dj)
        ob[(size_t)(16 * mi + 4 * g + r) * 5120 + 16 * dj + c] = f2bf(o[mi][dj][r] * inv);
    }
}

// ---------------- launch ----------------
extern "C" void kernel_launch(void* const* d_in, const int* in_sizes, int n_in,
                              void* d_out, int out_size, void* d_ws, size_t ws_size,
                              hipStream_t stream) {
  const float* x = (const float*)d_in[0];
  const float* sinp = (const float*)d_in[1];
  const float* cosp = (const float*)d_in[2];
  const float* norm_w = (const float*)d_in[3];
  const float* w_qkv = (const float*)d_in[4];
  const float* b_qkv = (const float*)d_in[5];
  const float* w_in = (const float*)d_in[6];
  const float* b_in = (const float*)d_in[7];
  const float* w_out = (const float*)d_in[8];
  const float* b_out = (const float*)d_in[9];
  float* out = (float*)d_out;

  char* ws = (char*)d_ws;
  u16* xn = (u16*)(ws);                        // 8192*1024*2      = 16,777,216
  u16* vT = (u16*)(ws);                        // aliases xn (xn dead after FF gemm)
  u16* qkv = (u16*)(ws + 16777216);            // 8192*3072*2      = 50,331,648
  u16* comb = (u16*)(ws + 67108864);           // 8192*5120*2      = 83,886,080
  u16* wqkvT = (u16*)(ws + 150994944);         // 3072*1024*2      = 6,291,456
  u16* winT = (u16*)(ws + 157286400);          // 4096*1024*2      = 8,388,608
  u16* woutT = (u16*)(ws + 165675008);         // 1024*5120*2      = 10,485,760

  transpose_f32_bf16<<<dim3(3072 / 32, 1024 / 32), 256, 0, stream>>>(w_qkv, wqkvT, 1024, 3072);
  transpose_f32_bf16<<<dim3(4096 / 32, 1024 / 32), 256, 0, stream>>>(w_in, winT, 1024, 4096);
  transpose_f32_bf16<<<dim3(1024 / 32, 5120 / 32), 256, 0, stream>>>(w_out, woutT, 5120, 1024);

  rmsnorm_kernel<<<8192, 256, 0, stream>>>(x, norm_w, xn);

  // qkv = xn @ w_qkv + b_qkv   (bf16 out)
  gemm_bt<<<dim3(3072 / 128, 8192 / 128), 256, 0, stream>>>(xn, wqkvT, b_qkv, qkv, 1024, 3072, 0);

  rope_kernel<<<32768, 256, 0, stream>>>(qkv, sinp, cosp);

  // ff = gelu(xn @ w_in + b_in) -> comb cols [1024, 5120)  (bf16 out; last use of xn)
  gemm_bt<<<dim3(4096 / 128, 8192 / 128), 256, 0, stream>>>(xn, winT, b_in, comb + 1024, 1024, 5120, 1);

  // vT[b,h][d][s] = V  (into xn's region)
  transpose_v<<<dim3(128, 2, 32), 256, 0, stream>>>(qkv, vT);

  attn_kernel<<<2048, 64, 0, stream>>>(qkv, vT, comb);

  // out = comb @ w_out + b_out  (f32 out)
  gemm_bt<<<dim3(1024 / 128, 8192 / 128), 256, 0, stream>>>(comb, woutT, b_out, out, 5120, 1024, 2);
}

// Round 5
// 461.899 us; speedup vs baseline: 1.1713x; 1.1135x over previous
//
#include <hip/hip_runtime.h>

typedef unsigned short u16;
typedef __attribute__((ext_vector_type(8))) short short8;
typedef __attribute__((ext_vector_type(4))) unsigned short u16x4;
typedef __attribute__((ext_vector_type(4))) float f32x4;

#define DEV __device__ __forceinline__

DEV float bf2f(u16 u) { return __uint_as_float(((unsigned int)u) << 16); }
DEV u16 f2bf(float f) {
  unsigned int u = __float_as_uint(f);
  u += 0x7FFF + ((u >> 16) & 1);
  return (u16)(u >> 16);
}

DEV float redmax16(float v) {
  v = fmaxf(v, __shfl_xor(v, 1));
  v = fmaxf(v, __shfl_xor(v, 2));
  v = fmaxf(v, __shfl_xor(v, 4));
  v = fmaxf(v, __shfl_xor(v, 8));
  return v;
}
DEV float redsum16(float v) {
  v += __shfl_xor(v, 1);
  v += __shfl_xor(v, 2);
  v += __shfl_xor(v, 4);
  v += __shfl_xor(v, 8);
  return v;
}

// ---------------- transpose + cast f32 -> bf16, 32x32 tiles ----------------
__global__ __launch_bounds__(256) void transpose_f32_bf16(const float* __restrict__ in,
                                                          u16* __restrict__ out,
                                                          int R, int C) {
  __shared__ u16 tile[32][33];
  int tx = threadIdx.x & 31, ty = threadIdx.x >> 5;  // 32 x 8
  int r0 = blockIdx.y * 32, c0 = blockIdx.x * 32;
#pragma unroll
  for (int i = 0; i < 32; i += 8)
    tile[ty + i][tx] = f2bf(in[(size_t)(r0 + ty + i) * C + c0 + tx]);
  __syncthreads();
#pragma unroll
  for (int i = 0; i < 32; i += 8)
    out[(size_t)(c0 + ty + i) * R + r0 + tx] = tile[tx][ty + i];
}

// ---------------- transpose V third of qkv -> vT[b,h][64][4096] -------------
__global__ __launch_bounds__(256) void transpose_v(const u16* __restrict__ qkv,
                                                   u16* __restrict__ vT) {
  __shared__ u16 tile[32][33];
  int tx = threadIdx.x & 31, ty = threadIdx.x >> 5;  // 32 x 8
  int s0 = blockIdx.x * 32, d0 = blockIdx.y * 32;
  int bh = blockIdx.z;
  const u16* src = qkv + (size_t)(bh >> 4) * 4096 * 3072 + 2048 + (bh & 15) * 64;
#pragma unroll
  for (int i = 0; i < 32; i += 8)
    tile[ty + i][tx] = src[(size_t)(s0 + ty + i) * 3072 + d0 + tx];
  __syncthreads();
  u16* dst = vT + (size_t)bh * 64 * 4096;
#pragma unroll
  for (int i = 0; i < 32; i += 8)
    dst[(size_t)(d0 + ty + i) * 4096 + s0 + tx] = tile[tx][ty + i];
}

// ---------------- RMSNorm: 8192 rows x 1024, f32 in -> bf16 out ----------------
__global__ __launch_bounds__(256) void rmsnorm_kernel(const float* __restrict__ x,
                                                      const float* __restrict__ w,
                                                      u16* __restrict__ xn) {
  int row = blockIdx.x, t = threadIdx.x;
  const float4* xr = reinterpret_cast<const float4*>(x + (size_t)row * 1024);
  float4 v = xr[t];
  float ss = v.x * v.x + v.y * v.y + v.z * v.z + v.w * v.w;
#pragma unroll
  for (int d = 1; d < 64; d <<= 1) ss += __shfl_xor(ss, d);
  __shared__ float red[4];
  if ((t & 63) == 0) red[t >> 6] = ss;
  __syncthreads();
  float tot = red[0] + red[1] + red[2] + red[3];
  float inv = rsqrtf(tot * (1.0f / 1024.0f) + 1e-6f);
  float4 wv = reinterpret_cast<const float4*>(w)[t];
  u16x4 o;
  o[0] = f2bf(v.x * inv * wv.x);
  o[1] = f2bf(v.y * inv * wv.y);
  o[2] = f2bf(v.z * inv * wv.z);
  o[3] = f2bf(v.w * inv * wv.w);
  *reinterpret_cast<u16x4*>(xn + (size_t)row * 1024 + t * 4) = o;
}

// ------- RoPE in-place on q,k halves of qkv (bf16); q additionally *0.125 ----
__global__ __launch_bounds__(256) void rope_kernel(u16* __restrict__ qkv,
                                                   const float* __restrict__ sp,
                                                   const float* __restrict__ cp) {
  size_t i = (size_t)blockIdx.x * 256 + threadIdx.x;  // pair index, 8192*1024 total
  int row = (int)(i >> 10);
  int e2 = (int)(i & 1023);
  int pos = row & 4095;
  int elem = e2 * 2;  // within [q(1024) | k(1024)]
  int d = elem & 63;
  size_t off = (size_t)row * 3072 + elem;
  float sc = (elem < 1024) ? 0.125f : 1.0f;  // fold 1/sqrt(64) into q (exact)
  float xe = bf2f(qkv[off]), xo = bf2f(qkv[off + 1]);
  float s0 = sp[pos * 64 + d], s1 = sp[pos * 64 + d + 1];
  float c0 = cp[pos * 64 + d], c1 = cp[pos * 64 + d + 1];
  qkv[off] = f2bf((xe * c0 - xo * s0) * sc);
  qkv[off + 1] = f2bf((xo * c1 + xe * s1) * sc);
}

// ============ Pipelined GEMM: C[M][N] = A[M][K] @ BT[N][K]^T + bias =========
// BM=256, BN=128, BK=64; 8 waves (4M x 2N), per-wave 64x64.
// Triple-buffered LDS (144 KB), staging issued 1 tile ahead of need,
// counted vmcnt(6) at tile boundary (never 0 in steady loop), T2 XOR swizzle,
// setprio around MFMA clusters, raw s_barrier (no vmcnt0 drains).
// grid (N/128, M/256), block 512.  mode 0: bf16; 1: bf16+GELU; 2: f32.

DEV void stage_half(const u16* __restrict__ gbase, int K, int kt, char* dst, int w, int l) {
  // 128 rows x 64k (16 KB). wave w covers segments s=2w,2w+1 (1 KB each, linear dest).
  // dest byte s*1024+16*l -> row = s*8 + (l>>3), dslot = l&7.
  // source k-slot pre-swizzled: ksrc = dslot ^ (row&7) = (l&7) ^ (l>>3).
#pragma unroll
  for (int j = 0; j < 2; ++j) {
    int s = w * 2 + j;
    int row = s * 8 + (l >> 3);
    int ksrc = ((l & 7) ^ (l >> 3)) << 3;
    const u16* src = gbase + (size_t)row * K + kt + ksrc;
    __builtin_amdgcn_global_load_lds(
        (const __attribute__((address_space(1))) unsigned int*)src,
        (__attribute__((address_space(3))) unsigned int*)(dst + s * 1024 + l * 16),
        16, 0, 0);
  }
}

DEV short8 ldfrag(const char* base, int row, int slot) {
  // swizzled read: byte = row*128 + ((slot ^ (row&7))<<4)
  return *reinterpret_cast<const short8*>(base + row * 128 + (((slot ^ (row & 7)) << 4)));
}

__global__ __launch_bounds__(512) void gemm256(const u16* __restrict__ A,
                                               const u16* __restrict__ BT,
                                               const float* __restrict__ bias,
                                               void* __restrict__ Cout,
                                               int K, int ldc, int mode) {
  __shared__ float4 lds_v[9216];  // 147456 B = 3 bufs x (A 32KB + B 16KB)
  char* lds = (char*)lds_v;
  int t = threadIdx.x;
  int w = t >> 6, l = t & 63, c = l & 15, g = l >> 4;
  int wr = w >> 1, wc = w & 1;
  size_t m0 = (size_t)blockIdx.y * 256, n0 = (size_t)blockIdx.x * 128;
  const u16* Ab = A + m0 * K;
  const u16* Bb = BT + n0 * K;
  int KT = K >> 6;

  f32x4 zero4 = {0.f, 0.f, 0.f, 0.f};
  f32x4 acc[4][4];
#pragma unroll
  for (int a = 0; a < 4; ++a)
#pragma unroll
    for (int b2 = 0; b2 < 4; ++b2) acc[a][b2] = zero4;

  // prologue: stage tiles 0 and 1 (6 loads each)
#pragma unroll
  for (int pt = 0; pt < 2; ++pt) {
    int boff = pt * 49152;
    stage_half(Ab, K, pt * 64, lds + boff, w, l);
    stage_half(Ab + (size_t)128 * K, K, pt * 64, lds + boff + 16384, w, l);
    stage_half(Bb, K, pt * 64, lds + boff + 32768, w, l);
  }
  asm volatile("s_waitcnt vmcnt(6)" ::: "memory");  // tile 0 landed
  __builtin_amdgcn_s_barrier();

  for (int tt = 0; tt < KT; ++tt) {
    const char* Abuf = lds + (tt % 3) * 49152;
    const char* Bbuf = Abuf + 32768;
    int b2off = ((tt + 2) % 3) * 49152;
    int kt2 = (tt + 2) * 64;
    bool pf = (tt + 2 < KT);

    // ---- phase 0 (kk=0): prefetch A halves of t+2, compute kk=0 ----
    if (pf) {
      stage_half(Ab, K, kt2, lds + b2off, w, l);
      stage_half(Ab + (size_t)128 * K, K, kt2, lds + b2off + 16384, w, l);
    }
    {
      short8 bv[4], av[4];
#pragma unroll
      for (int nj = 0; nj < 4; ++nj) bv[nj] = ldfrag(Bbuf, wc * 64 + 16 * nj + c, g);
#pragma unroll
      for (int mi = 0; mi < 4; ++mi) av[mi] = ldfrag(Abuf, wr * 64 + 16 * mi + c, g);
      __builtin_amdgcn_s_setprio(1);
#pragma unroll
      for (int mi = 0; mi < 4; ++mi)
#pragma unroll
        for (int nj = 0; nj < 4; ++nj)
          acc[mi][nj] = __builtin_amdgcn_mfma_f32_16x16x32_bf16(av[mi], bv[nj], acc[mi][nj], 0, 0, 0);
      __builtin_amdgcn_s_setprio(0);
    }
    __builtin_amdgcn_s_barrier();

    // ---- phase 1 (kk=1): prefetch B half of t+2, compute kk=1 ----
    if (pf) stage_half(Bb, K, kt2, lds + b2off + 32768, w, l);
    {
      short8 bv[4], av[4];
#pragma unroll
      for (int nj = 0; nj < 4; ++nj) bv[nj] = ldfrag(Bbuf, wc * 64 + 16 * nj + c, 4 + g);
#pragma unroll
      for (int mi = 0; mi < 4; ++mi) av[mi] = ldfrag(Abuf, wr * 64 + 16 * mi + c, 4 + g);
      __builtin_amdgcn_s_setprio(1);
#pragma unroll
      for (int mi = 0; mi < 4; ++mi)
#pragma unroll
        for (int nj = 0; nj < 4; ++nj)
          acc[mi][nj] = __builtin_amdgcn_mfma_f32_16x16x32_bf16(av[mi], bv[nj], acc[mi][nj], 0, 0, 0);
      __builtin_amdgcn_s_setprio(0);
    }
    if (tt + 1 < KT) {
      // boundary: tile t+1 must be fully landed; t+2's 6 loads may fly
      if (pf)
        asm volatile("s_waitcnt vmcnt(6)" ::: "memory");
      else
        asm volatile("s_waitcnt vmcnt(0)" ::: "memory");
      __builtin_amdgcn_s_barrier();
    }
  }

  // ---- epilogue ----
#pragma unroll
  for (int nj = 0; nj < 4; ++nj) {
    int col = (int)n0 + wc * 64 + 16 * nj + c;
    float bvv = bias[col];
#pragma unroll
    for (int mi = 0; mi < 4; ++mi) {
      size_t rbase = m0 + wr * 64 + 16 * mi + 4 * g;
#pragma unroll
      for (int r = 0; r < 4; ++r) {
        float f = acc[mi][nj][r] + bvv;
        if (mode == 1) f = 0.5f * f * (1.0f + erff(f * 0.70710678f));
        size_t oidx = (rbase + r) * (size_t)ldc + col;
        if (mode == 2)
          ((float*)Cout)[oidx] = f;
        else
          ((u16*)Cout)[oidx] = f2bf(f);
      }
    }
  }
}

// ---------------- sliding-window causal attention ----------------
// 1 wave per 64-query tile, no barriers. grid = 2048, block = 64.
// Q pre-scaled by 0.125. K frags direct global; V frags direct from vT.
__global__ __launch_bounds__(64) void attn_kernel(const u16* __restrict__ qkv,
                                                  const u16* __restrict__ vT,
                                                  u16* __restrict__ comb) {
  int wg = blockIdx.x;
  int qt = wg & 63, h = (wg >> 6) & 15, b = wg >> 10;
  int l = threadIdx.x, c = l & 15, g = l >> 4;
  int q0 = qt * 64;
  const u16* qb = qkv + (size_t)b * 4096 * 3072 + h * 64;
  const u16* kb = qb + 1024;
  const u16* vt = vT + (size_t)(b * 16 + h) * 64 * 4096;
  __shared__ u16 Pl[64 * 72];

  short8 qf[4][2];
#pragma unroll
  for (int mi = 0; mi < 4; ++mi)
#pragma unroll
    for (int kk = 0; kk < 2; ++kk)
      qf[mi][kk] = *reinterpret_cast<const short8*>(
          qb + (size_t)(q0 + 16 * mi + c) * 3072 + 32 * kk + 8 * g);

  f32x4 zero4 = {0.f, 0.f, 0.f, 0.f};
  f32x4 o[4][4];
  float mr[4][4], lr[4][4];
#pragma unroll
  for (int a = 0; a < 4; ++a)
#pragma unroll
    for (int d2 = 0; d2 < 4; ++d2) {
      o[a][d2] = zero4;
      mr[a][d2] = -1e30f;
      lr[a][d2] = 0.f;
    }

  int t_lo = qt >= 8 ? qt - 8 : 0;
  for (int tt = t_lo; tt <= qt; ++tt) {
    int kt0 = tt * 64;
    f32x4 s[4][4];
#pragma unroll
    for (int a = 0; a < 4; ++a)
#pragma unroll
      for (int d2 = 0; d2 < 4; ++d2) s[a][d2] = zero4;

#pragma unroll
    for (int kk = 0; kk < 2; ++kk) {
      short8 kf[4];
#pragma unroll
      for (int nj = 0; nj < 4; ++nj)
        kf[nj] = *reinterpret_cast<const short8*>(
            kb + (size_t)(kt0 + 16 * nj + c) * 3072 + 32 * kk + 8 * g);
#pragma unroll
      for (int mi = 0; mi < 4; ++mi)
#pragma unroll
        for (int nj = 0; nj < 4; ++nj)
          s[mi][nj] = __builtin_amdgcn_mfma_f32_16x16x32_bf16(qf[mi][kk], kf[nj], s[mi][nj], 0, 0, 0);
    }

    // mask only on the 2 boundary tiles (wave-uniform branch)
    bool mc = (tt == qt), mw = (tt == qt - 8);
    if (mc | mw) {
#pragma unroll
      for (int mi = 0; mi < 4; ++mi)
#pragma unroll
        for (int nj = 0; nj < 4; ++nj)
#pragma unroll
          for (int r = 0; r < 4; ++r) {
            int qg = q0 + 16 * mi + 4 * g + r;
            int kg = kt0 + 16 * nj + c;
            if ((mc && kg > qg) || (mw && qg - kg >= 512)) s[mi][nj][r] = -1e30f;
          }
    }

#pragma unroll
    for (int mi = 0; mi < 4; ++mi)
#pragma unroll
      for (int r = 0; r < 4; ++r) {
        float tm = fmaxf(fmaxf(s[mi][0][r], s[mi][1][r]), fmaxf(s[mi][2][r], s[mi][3][r]));
        tm = redmax16(tm);
        float mn = fmaxf(mr[mi][r], tm);
        float a = __expf(mr[mi][r] - mn);
        mr[mi][r] = mn;
        float rs = 0.f;
        u16* pp = &Pl[(16 * mi + 4 * g + r) * 72 + c];
#pragma unroll
        for (int nj = 0; nj < 4; ++nj) {
          float p = __expf(s[mi][nj][r] - mn);
          rs += p;
          pp[16 * nj] = f2bf(p);  // natural k order, imm-offset ds_write_b16
        }
        rs = redsum16(rs);
        lr[mi][r] = lr[mi][r] * a + rs;
#pragma unroll
        for (int dj = 0; dj < 4; ++dj) o[mi][dj][r] *= a;
      }

    // PV: A-frag from Pl (natural order), B-frag = k-contiguous rows of vT
#pragma unroll
    for (int kk = 0; kk < 2; ++kk) {
      short8 pa[4];
#pragma unroll
      for (int mi = 0; mi < 4; ++mi)
        pa[mi] = *reinterpret_cast<const short8*>(&Pl[(16 * mi + c) * 72 + 32 * kk + 8 * g]);
      short8 bv[4];
#pragma unroll
      for (int dj = 0; dj < 4; ++dj)
        bv[dj] = *reinterpret_cast<const short8*>(
            vt + (size_t)(16 * dj + c) * 4096 + kt0 + 32 * kk + 8 * g);
#pragma unroll
      for (int mi = 0; mi < 4; ++mi)
#pragma unroll
        for (int dj = 0; dj < 4; ++dj)
          o[mi][dj] = __builtin_amdgcn_mfma_f32_16x16x32_bf16(pa[mi], bv[dj], o[mi][dj], 0, 0, 0);
    }
  }

  u16* ob = comb + (size_t)(b * 4096 + q0) * 5120 + h * 64;
#pragma unroll
  for (int mi = 0; mi < 4; ++mi)
#pragma unroll
    for (int r = 0; r < 4; ++r) {
      float inv = __builtin_amdgcn_rcpf(lr[mi][r]);
#pragma unroll
      for (int dj = 0; dj < 4; ++dj)
        ob[(size_t)(16 * mi + 4 * g + r) * 5120 + 16 * dj + c] = f2bf(o[mi][dj][r] * inv);
    }
}

// ---------------- launch ----------------
extern "C" void kernel_launch(void* const* d_in, const int* in_sizes, int n_in,
                              void* d_out, int out_size, void* d_ws, size_t ws_size,
                              hipStream_t stream) {
  const float* x = (const float*)d_in[0];
  const float* sinp = (const float*)d_in[1];
  const float* cosp = (const float*)d_in[2];
  const float* norm_w = (const float*)d_in[3];
  const float* w_qkv = (const float*)d_in[4];
  const float* b_qkv = (const float*)d_in[5];
  const float* w_in = (const float*)d_in[6];
  const float* b_in = (const float*)d_in[7];
  const float* w_out = (const float*)d_in[8];
  const float* b_out = (const float*)d_in[9];
  float* out = (float*)d_out;

  char* ws = (char*)d_ws;
  u16* xn = (u16*)(ws);                        // 8192*1024*2      = 16,777,216
  u16* vT = (u16*)(ws);                        // aliases xn (xn dead after FF gemm)
  u16* qkv = (u16*)(ws + 16777216);            // 8192*3072*2      = 50,331,648
  u16* comb = (u16*)(ws + 67108864);           // 8192*5120*2      = 83,886,080
  u16* wqkvT = (u16*)(ws + 150994944);         // 3072*1024*2      = 6,291,456
  u16* winT = (u16*)(ws + 157286400);          // 4096*1024*2      = 8,388,608
  u16* woutT = (u16*)(ws + 165675008);         // 1024*5120*2      = 10,485,760

  transpose_f32_bf16<<<dim3(3072 / 32, 1024 / 32), 256, 0, stream>>>(w_qkv, wqkvT, 1024, 3072);
  transpose_f32_bf16<<<dim3(4096 / 32, 1024 / 32), 256, 0, stream>>>(w_in, winT, 1024, 4096);
  transpose_f32_bf16<<<dim3(1024 / 32, 5120 / 32), 256, 0, stream>>>(w_out, woutT, 5120, 1024);

  rmsnorm_kernel<<<8192, 256, 0, stream>>>(x, norm_w, xn);

  // qkv = xn @ w_qkv + b_qkv   (bf16 out)
  gemm256<<<dim3(3072 / 128, 8192 / 256), 512, 0, stream>>>(xn, wqkvT, b_qkv, qkv, 1024, 3072, 0);

  rope_kernel<<<32768, 256, 0, stream>>>(qkv, sinp, cosp);

  // ff = gelu(xn @ w_in + b_in) -> comb cols [1024, 5120)  (bf16 out; last use of xn)
  gemm256<<<dim3(4096 / 128, 8192 / 256), 512, 0, stream>>>(xn, winT, b_in, comb + 1024, 1024, 5120, 1);

  // vT[b,h][d][s] = V  (into xn's region)
  transpose_v<<<dim3(128, 2, 32), 256, 0, stream>>>(qkv, vT);

  attn_kernel<<<2048, 64, 0, stream>>>(qkv, vT, comb);

  // out = comb @ w_out + b_out  (f32 out)
  gemm256<<<dim3(1024 / 128, 8192 / 256), 512, 0, stream>>>(comb, woutT, b_out, out, 5120, 1024, 2);
}